// Round 11
// baseline (409.004 us; speedup 1.0000x reference)
//
#include <hip/hip_runtime.h>
#include <hip/hip_bf16.h>
#include <stdint.h>
#include <stddef.h>

#define SEQL 2048
#define DIMSZ 2048
#define HN 16
#define DKD 128
#define DVD 128
#define QSCALE 0.08838834764831843f   // 128^-0.5

typedef __attribute__((ext_vector_type(4))) float f32x4;
typedef __attribute__((ext_vector_type(2))) float f32x2;
typedef __attribute__((ext_vector_type(8))) short bf16x8;

__device__ __forceinline__ float sigmoid_f(float x) { return 1.f / (1.f + __expf(-x)); }

// ---------------- bf16 GEMM: C[M,N] (f32) = A[M,K]bf16 @ Bt[N,K]bf16 ----------------
#define BM 128
#define BN 128
#define BKK 64

__global__ __launch_bounds__(256) void gemm_bt(
    const __hip_bfloat16* __restrict__ A, const __hip_bfloat16* __restrict__ B,
    float* __restrict__ C, int M, int N, int lda, int ldb, int klen, int accum)
{
  __shared__ __hip_bfloat16 As[BM * BKK];
  __shared__ __hip_bfloat16 Bs[BN * BKK];
  const int tid = threadIdx.x;
  const int lane = tid & 63;
  const int w = tid >> 6;
  const int wm = w >> 1, wn = w & 1;            // 2x2 wave grid, 64x64 each
  const int m0 = blockIdx.y * BM, n0 = blockIdx.x * BN;
  const int l15 = lane & 15, l4 = lane >> 4;
  const int kbase = blockIdx.z * klen;

  f32x4 acc[4][4] = {};

  for (int k0 = kbase; k0 < kbase + klen; k0 += BKK) {
#pragma unroll
    for (int i = 0; i < 4; ++i) {
      const int c = (w * 4 + i) * 64 + lane;     // chunk id, 16B each; 8 chunks/row
      const int row = c >> 3;
      const int colb = (c & 7) * 8;
      __builtin_amdgcn_global_load_lds(
          (const __attribute__((address_space(1))) void*)(A + (size_t)(m0 + row) * lda + k0 + colb),
          (__attribute__((address_space(3))) void*)(As + (size_t)c * 8), 16, 0, 0);
      __builtin_amdgcn_global_load_lds(
          (const __attribute__((address_space(1))) void*)(B + (size_t)(n0 + row) * ldb + k0 + colb),
          (__attribute__((address_space(3))) void*)(Bs + (size_t)c * 8), 16, 0, 0);
    }
    __syncthreads();
#pragma unroll
    for (int kk = 0; kk < BKK; kk += 32) {
      bf16x8 af[4], bfv[4];
#pragma unroll
      for (int mi = 0; mi < 4; ++mi)
        af[mi] = *(const bf16x8*)(As + (wm * 64 + mi * 16 + l15) * BKK + kk + l4 * 8);
#pragma unroll
      for (int ni = 0; ni < 4; ++ni)
        bfv[ni] = *(const bf16x8*)(Bs + (wn * 64 + ni * 16 + l15) * BKK + kk + l4 * 8);
#pragma unroll
      for (int mi = 0; mi < 4; ++mi)
#pragma unroll
        for (int ni = 0; ni < 4; ++ni)
          acc[mi][ni] = __builtin_amdgcn_mfma_f32_16x16x32_bf16(af[mi], bfv[ni], acc[mi][ni], 0, 0, 0);
    }
    __syncthreads();
  }

  float* Cz = C + (size_t)blockIdx.z * M * N;
#pragma unroll
  for (int mi = 0; mi < 4; ++mi) {
#pragma unroll
    for (int ni = 0; ni < 4; ++ni) {
      const int row = m0 + wm * 64 + mi * 16 + l4 * 4;
      const int col = n0 + wn * 64 + ni * 16 + l15;
#pragma unroll
      for (int r = 0; r < 4; ++r) {
        size_t idx = (size_t)(row + r) * N + col;
        if (accum) Cz[idx] += acc[mi][ni][r];
        else Cz[idx] = acc[mi][ni][r];
      }
    }
  }
}

// ---------------- 256x256 8-phase GEMM (T2+T3+T4+T5); split-K via blockIdx.z ----------------
#define PHASE256(MQ, NQ, NEEDA, NEEDB)                                          \
  {                                                                             \
    if (NEEDA) {                                                                \
      _Pragma("unroll") for (int m2 = 0; m2 < 4; ++m2)                          \
      _Pragma("unroll") for (int ks = 0; ks < 2; ++ks) {                        \
        const int la = (MQ) * 128 + wm * 64 + m2 * 16 + l15;                    \
        const int kc = ks * 4 + l4;                                             \
        a[m2][ks] = *(const bf16x8*)(lds + cb + la * 64 + (kc ^ (la & 7)) * 8); \
      }                                                                         \
    }                                                                           \
    if (NEEDB) {                                                                \
      _Pragma("unroll") for (int n2 = 0; n2 < 2; ++n2)                          \
      _Pragma("unroll") for (int ks = 0; ks < 2; ++ks) {                        \
        const int lb = (NQ) * 128 + wn * 32 + n2 * 16 + l15;                    \
        const int kc = ks * 4 + l4;                                             \
        b[n2][ks] = *(const bf16x8*)(lds + cb + 16384 + lb * 64 + (kc ^ (lb & 7)) * 8); \
      }                                                                         \
    }                                                                           \
    __builtin_amdgcn_s_setprio(1);                                              \
    _Pragma("unroll") for (int m2 = 0; m2 < 4; ++m2)                            \
    _Pragma("unroll") for (int n2 = 0; n2 < 2; ++n2)                            \
    _Pragma("unroll") for (int ks = 0; ks < 2; ++ks)                            \
      acc[(MQ) * 4 + m2][(NQ) * 2 + n2] = __builtin_amdgcn_mfma_f32_16x16x32_bf16( \
          a[m2][ks], b[n2][ks], acc[(MQ) * 4 + m2][(NQ) * 2 + n2], 0, 0, 0);    \
    __builtin_amdgcn_s_setprio(0);                                              \
  }

__global__ __launch_bounds__(512, 2) void gemm_bt256(
    const __hip_bfloat16* __restrict__ A, const __hip_bfloat16* __restrict__ B,
    float* __restrict__ C, int M, int N, int lda, int ldb, int NT)
{
  __shared__ __hip_bfloat16 lds[65536];   // 128 KiB
  const int tid = threadIdx.x;
  const int w = tid >> 6, lane = tid & 63;
  const int wm = w >> 2, wn = w & 3;
  const int l15 = lane & 15, l4 = lane >> 4;
  const int m0 = blockIdx.y * 256, n0 = blockIdx.x * 256;
  const int kb0 = blockIdx.z * NT;

  f32x4 acc[8][4] = {};
  bf16x8 a[4][2], b[2][2];

  auto stage_half = [&](int which, int t1) {
    const int buf = t1 & 1;
    const int k0n = (kb0 + ((t1 < NT) ? t1 : 0)) * 64;
    const int mat = which & 1;          // 0=A, 1=B
    const int half = which >> 1;
#pragma unroll
    for (int i = 0; i < 2; ++i) {
      const int c = i * 512 + tid;           // chunk 0..1023 within half (16B each)
      const int l = half * 128 + (c >> 3);   // lds row 0..255 (quadrant-grouped)
      const int kcs = (c & 7) ^ (l & 7);     // pre-swizzled source chunk
      const __hip_bfloat16* src;
      if (mat == 0) {
        const int grow = ((l >> 6) & 1) * 128 + (l >> 7) * 64 + (l & 63);
        src = A + (size_t)(m0 + grow) * lda + k0n + kcs * 8;
      } else {
        const int gcol = ((l >> 5) & 3) * 64 + (l >> 7) * 32 + (l & 31);
        src = B + (size_t)(n0 + gcol) * ldb + k0n + kcs * 8;
      }
      __builtin_amdgcn_global_load_lds(
          (const __attribute__((address_space(1))) void*)src,
          (__attribute__((address_space(3))) void*)(lds + (size_t)buf * 32768 + mat * 16384 + half * 8192 + (size_t)c * 8),
          16, 0, 0);
    }
  };

  stage_half(0, 0); stage_half(1, 0); stage_half(2, 0); stage_half(3, 0);

  for (int t = 0; t < NT; ++t) {
    const size_t cb = (size_t)(t & 1) * 32768;
    stage_half(0, t + 1);
    asm volatile("s_waitcnt vmcnt(6)" ::: "memory");
    __builtin_amdgcn_s_barrier();
    __builtin_amdgcn_sched_barrier(0);
    PHASE256(0, 0, 1, 1)
    __builtin_amdgcn_s_barrier();
    stage_half(1, t + 1);
    asm volatile("s_waitcnt vmcnt(4)" ::: "memory");
    __builtin_amdgcn_s_barrier();
    __builtin_amdgcn_sched_barrier(0);
    PHASE256(0, 1, 0, 1)
    __builtin_amdgcn_s_barrier();
    stage_half(2, t + 1);
    __builtin_amdgcn_s_barrier();
    __builtin_amdgcn_sched_barrier(0);
    PHASE256(1, 1, 1, 0)
    __builtin_amdgcn_s_barrier();
    stage_half(3, t + 1);
    __builtin_amdgcn_s_barrier();
    __builtin_amdgcn_sched_barrier(0);
    PHASE256(1, 0, 0, 1)
    __builtin_amdgcn_s_barrier();
  }
  asm volatile("s_waitcnt vmcnt(0)" ::: "memory");

  float* Cz = C + (size_t)blockIdx.z * M * N;
#pragma unroll
  for (int mi = 0; mi < 8; ++mi) {
#pragma unroll
    for (int ni = 0; ni < 4; ++ni) {
      const int row = m0 + wm * 128 + mi * 16 + l4 * 4;
      const int col = n0 + wn * 64 + ni * 16 + l15;
#pragma unroll
      for (int r = 0; r < 4; ++r)
        Cz[(size_t)(row + r) * N + col] = acc[mi][ni][r];
    }
  }
}

// ---------------- 2-partial reduce-add ----------------
__global__ __launch_bounds__(256) void reduce2_kernel(
    const float* __restrict__ part, float* __restrict__ out, int n4)
{
  int idx = blockIdx.x * 256 + threadIdx.x;
  if (idx >= n4) return;
  const size_t chunk = (size_t)SEQL * DIMSZ;
  f32x4 a = *(const f32x4*)(part + (size_t)idx * 4);
  f32x4 b = *(const f32x4*)(part + chunk + (size_t)idx * 4);
  a.x += b.x; a.y += b.y; a.z += b.z; a.w += b.w;
  *(f32x4*)(out + (size_t)idx * 4) = a;
}

// ---------------- fused split-precision GEMM: C = Ah@Bh + Ah@Bl + Al@Bh ----------------
__global__ __launch_bounds__(256) void gemm_btsplit(
    const __hip_bfloat16* __restrict__ Ah, const __hip_bfloat16* __restrict__ Al,
    const __hip_bfloat16* __restrict__ Bh, const __hip_bfloat16* __restrict__ Bl,
    float* __restrict__ C, int M, int N, int lda, int ldb, int klen)
{
  __shared__ __hip_bfloat16 Ash[BM * BKK];
  __shared__ __hip_bfloat16 Asl[BM * BKK];
  __shared__ __hip_bfloat16 Bsh[BN * BKK];
  __shared__ __hip_bfloat16 Bsl[BN * BKK];
  const int tid = threadIdx.x;
  const int lane = tid & 63;
  const int w = tid >> 6;
  const int wm = w >> 1, wn = w & 1;
  const int m0 = blockIdx.y * BM, n0 = blockIdx.x * BN;
  const int l15 = lane & 15, l4 = lane >> 4;
  const int kbase = blockIdx.z * klen;

  f32x4 acc[4][4] = {};

  for (int k0 = kbase; k0 < kbase + klen; k0 += BKK) {
#pragma unroll
    for (int i = 0; i < 4; ++i) {
      const int c = (w * 4 + i) * 64 + lane;
      const int row = c >> 3;
      const int colb = (c & 7) * 8;
      const size_t go = (size_t)(m0 + row) * lda + k0 + colb;
      const size_t gn = (size_t)(n0 + row) * ldb + k0 + colb;
      __builtin_amdgcn_global_load_lds(
          (const __attribute__((address_space(1))) void*)(Ah + go),
          (__attribute__((address_space(3))) void*)(Ash + (size_t)c * 8), 16, 0, 0);
      __builtin_amdgcn_global_load_lds(
          (const __attribute__((address_space(1))) void*)(Al + go),
          (__attribute__((address_space(3))) void*)(Asl + (size_t)c * 8), 16, 0, 0);
      __builtin_amdgcn_global_load_lds(
          (const __attribute__((address_space(1))) void*)(Bh + gn),
          (__attribute__((address_space(3))) void*)(Bsh + (size_t)c * 8), 16, 0, 0);
      __builtin_amdgcn_global_load_lds(
          (const __attribute__((address_space(1))) void*)(Bl + gn),
          (__attribute__((address_space(3))) void*)(Bsl + (size_t)c * 8), 16, 0, 0);
    }
    __syncthreads();
#pragma unroll
    for (int kk = 0; kk < BKK; kk += 32) {
      bf16x8 afh[4], afl[4], bfh[4], bfl[4];
#pragma unroll
      for (int mi = 0; mi < 4; ++mi) {
        const int ao = (wm * 64 + mi * 16 + l15) * BKK + kk + l4 * 8;
        afh[mi] = *(const bf16x8*)(Ash + ao);
        afl[mi] = *(const bf16x8*)(Asl + ao);
      }
#pragma unroll
      for (int ni = 0; ni < 4; ++ni) {
        const int bo = (wn * 64 + ni * 16 + l15) * BKK + kk + l4 * 8;
        bfh[ni] = *(const bf16x8*)(Bsh + bo);
        bfl[ni] = *(const bf16x8*)(Bsl + bo);
      }
#pragma unroll
      for (int mi = 0; mi < 4; ++mi)
#pragma unroll
        for (int ni = 0; ni < 4; ++ni) {
          acc[mi][ni] = __builtin_amdgcn_mfma_f32_16x16x32_bf16(afh[mi], bfh[ni], acc[mi][ni], 0, 0, 0);
          acc[mi][ni] = __builtin_amdgcn_mfma_f32_16x16x32_bf16(afh[mi], bfl[ni], acc[mi][ni], 0, 0, 0);
          acc[mi][ni] = __builtin_amdgcn_mfma_f32_16x16x32_bf16(afl[mi], bfh[ni], acc[mi][ni], 0, 0, 0);
        }
    }
    __syncthreads();
  }

  float* Cz = C + (size_t)blockIdx.z * M * N;
#pragma unroll
  for (int mi = 0; mi < 4; ++mi) {
#pragma unroll
    for (int ni = 0; ni < 4; ++ni) {
      const int row = m0 + wm * 64 + mi * 16 + l4 * 4;
      const int col = n0 + wn * 64 + ni * 16 + l15;
#pragma unroll
      for (int r = 0; r < 4; ++r)
        Cz[(size_t)(row + r) * N + col] = acc[mi][ni][r];
    }
  }
}

// ---------------- transpose + cast (optional hi/lo split): out[C,R] = bf16(in[R,C]^T) ----------------
__global__ __launch_bounds__(256) void transpose_cast_kernel(
    const float* __restrict__ in, __hip_bfloat16* __restrict__ outT,
    __hip_bfloat16* __restrict__ outLo, int R, int C)
{
  __shared__ float tile[32][33];
  const int c0 = blockIdx.x * 32, r0 = blockIdx.y * 32;
  const int tc = threadIdx.x & 31, tr = threadIdx.x >> 5;   // tr in 0..7
#pragma unroll
  for (int i = 0; i < 4; ++i)
    tile[tr + i * 8][tc] = in[(size_t)(r0 + tr + i * 8) * C + c0 + tc];
  __syncthreads();
#pragma unroll
  for (int i = 0; i < 4; ++i) {
    float val = tile[tc][tr + i * 8];
    __hip_bfloat16 h = __float2bfloat16(val);
    size_t oi = (size_t)(c0 + tr + i * 8) * R + r0 + tc;
    outT[oi] = h;
    if (outLo) outLo[oi] = __float2bfloat16(val - __bfloat162float(h));
  }
}

// ---------------- elementwise cast with optional lo residual ----------------
__global__ __launch_bounds__(256) void cast_split_kernel(
    const float* __restrict__ in, __hip_bfloat16* __restrict__ hi,
    __hip_bfloat16* __restrict__ lo, int n4)
{
  int idx = blockIdx.x * 256 + threadIdx.x;
  if (idx >= n4) return;
  f32x4 v = *(const f32x4*)(in + (size_t)idx * 4);
  union { __hip_bfloat16 b[4]; unsigned long long u; } ph, pl;
#pragma unroll
  for (int j = 0; j < 4; ++j) {
    float f = v[j];
    __hip_bfloat16 hh = __float2bfloat16(f);
    ph.b[j] = hh;
    pl.b[j] = __float2bfloat16(f - __bfloat162float(hh));
  }
  *(unsigned long long*)((char*)hi + (size_t)idx * 8) = ph.u;
  if (lo) *(unsigned long long*)((char*)lo + (size_t)idx * 8) = pl.u;
}

// ---------------- split-K reduce (8 partials) -> bf16 hi (+ optional lo) ----------------
__global__ __launch_bounds__(256) void reduce8_kernel(
    const float* __restrict__ part, __hip_bfloat16* __restrict__ hi,
    __hip_bfloat16* __restrict__ lo, int n4, size_t chunk)
{
  int idx = blockIdx.x * 256 + threadIdx.x;
  if (idx >= n4) return;
  f32x4 a = *(const f32x4*)(part + (size_t)idx * 4);
#pragma unroll
  for (int z = 1; z < 8; ++z) {
    f32x4 b = *(const f32x4*)(part + z * chunk + (size_t)idx * 4);
    a.x += b.x; a.y += b.y; a.z += b.z; a.w += b.w;
  }
  union { __hip_bfloat16 b[4]; unsigned long long u; } ph, pl;
#pragma unroll
  for (int j = 0; j < 4; ++j) {
    float f = a[j];
    __hip_bfloat16 hh = __float2bfloat16(f);
    ph.b[j] = hh;
    pl.b[j] = __float2bfloat16(f - __bfloat162float(hh));
  }
  *(unsigned long long*)((char*)hi + (size_t)idx * 8) = ph.u;
  if (lo) *(unsigned long long*)((char*)lo + (size_t)idx * 8) = pl.u;
}

// ---------------- beta = sigmoid(x @ Wb), thread per (s,h); writes [h][s] ----------------
__global__ __launch_bounds__(256) void beta_kernel(
    const float* __restrict__ x, const float* __restrict__ Wb, float* __restrict__ betaT)
{
  int idx = blockIdx.x * 256 + threadIdx.x;      // 0..32767
  int s = idx >> 4, h = idx & 15;
  const float* xr = x + (size_t)s * DIMSZ;
  float acc = 0.f;
  for (int d = 0; d < DIMSZ; d += 4) {
    f32x4 xv = *(const f32x4*)(xr + d);
    acc = fmaf(xv.x, Wb[(size_t)(d + 0) * HN + h], acc);
    acc = fmaf(xv.y, Wb[(size_t)(d + 1) * HN + h], acc);
    acc = fmaf(xv.z, Wb[(size_t)(d + 2) * HN + h], acc);
    acc = fmaf(xv.w, Wb[(size_t)(d + 3) * HN + h], acc);
  }
  betaT[(size_t)h * SEQL + s] = 1.f / (1.f + expf(-acc));
}

// ---------------- fused prep + chunk-local precompute (C=32) ----------------
// Phase 2 rows INTERLEAVED across waves (tt = w + 4*tg): critical-wave pair count
// drops 220 -> 136 vs block-grouped. Slice-20 LDS layout keeps i-broadcast reads
// conflict-free. uv/oloc outputs stored bf16 (consumers round to bf16 anyway).
#define SL20(r, d) ((r) * 160 + ((d) >> 4) * 20 + ((d) & 15))

__global__ __launch_bounds__(256) void kda_pref(
    const float* __restrict__ qkv, const float* __restrict__ ve,
    const float* __restrict__ lam,
    const float* __restrict__ cwq, const float* __restrict__ cwk, const float* __restrict__ cwv,
    const float* __restrict__ gbuf,
    const float* __restrict__ dtb, const float* __restrict__ A_log,
    const float* __restrict__ betaT,
    __hip_bfloat16* __restrict__ Xgh, __hip_bfloat16* __restrict__ KTh,
    __hip_bfloat16* __restrict__ uvS, __hip_bfloat16* __restrict__ olocS,
    float* __restrict__ Pg)
{
  __shared__ float GL2[32 * 160];
  __shared__ float kL2[32 * 160];
  __shared__ float qL2[32 * 132];
  __shared__ float vL2[32 * 128];
  __shared__ float ALB[32][33];      // lower: A; upper [i][t]: B[t][i] (i<t)
  __shared__ float Bdiag[32], betaL[32];
  __shared__ float csumW[4 * 128];

  const int bid = blockIdx.x;
  const int h = bid >> 6, cc = bid & 63;
  const int tid = threadIdx.x;
  const int w = tid >> 6, lane = tid & 63;
  const size_t hc = (size_t)h * 64 + cc;
  const float Aexp = __expf(A_log[h]);

  // ======== phase 1: conv + silu + mix + l2norm + glog ========
  {
    const int c = lane * 2;                 // col pair
    const int r0g = cc * 32 + w * 8;        // global row base for this wave
    const int cg = h * 128 + c;

    f32x4 wq0 = *(const f32x4*)(cwq + (size_t)cg * 4), wq1 = *(const f32x4*)(cwq + (size_t)(cg + 1) * 4);
    f32x4 wk0 = *(const f32x4*)(cwk + (size_t)cg * 4), wk1 = *(const f32x4*)(cwk + (size_t)(cg + 1) * 4);
    f32x4 wv0 = *(const f32x4*)(cwv + (size_t)cg * 4), wv1 = *(const f32x4*)(cwv + (size_t)(cg + 1) * 4);
    f32x2 dt2 = *(const f32x2*)(dtb + cg);
    const float l0 = lam[0], l1 = lam[1];

    f32x2 xqr[11], xkr[11], xvr[11];
#pragma unroll
    for (int i = 0; i < 11; ++i) {
      const int sr = r0g - 3 + i;
      if (sr >= 0) {
        const size_t ro = (size_t)sr * 6144 + cg;
        xqr[i] = *(const f32x2*)(qkv + ro);
        xkr[i] = *(const f32x2*)(qkv + 2048 + ro);
        xvr[i] = *(const f32x2*)(qkv + 4096 + ro);
      } else {
        xqr[i].x = xqr[i].y = xkr[i].x = xkr[i].y = xvr[i].x = xvr[i].y = 0.f;
      }
    }

    float gl0[8], gl1[8];
#pragma unroll
    for (int i = 0; i < 8; ++i) {
      const int rr = r0g + i;
      const int lr = w * 8 + i;
      float aq0 = 0, aq1 = 0, ak0 = 0, ak1 = 0, av0 = 0, av1 = 0;
#pragma unroll
      for (int j = 0; j < 4; ++j) {
        aq0 = fmaf(xqr[i + j].x, wq0[j], aq0); aq1 = fmaf(xqr[i + j].y, wq1[j], aq1);
        ak0 = fmaf(xkr[i + j].x, wk0[j], ak0); ak1 = fmaf(xkr[i + j].y, wk1[j], ak1);
        av0 = fmaf(xvr[i + j].x, wv0[j], av0); av1 = fmaf(xvr[i + j].y, wv1[j], av1);
      }
      float yq0 = aq0 * sigmoid_f(aq0), yq1 = aq1 * sigmoid_f(aq1);
      float yk0 = ak0 * sigmoid_f(ak0), yk1 = ak1 * sigmoid_f(ak1);
      float yv0 = av0 * sigmoid_f(av0), yv1 = av1 * sigmoid_f(av1);

      f32x2 vev = *(const f32x2*)(ve + ((size_t)rr * HN + h) * 128 + c);
      float v0 = l0 * yv0 + l1 * vev.x;
      float v1 = l0 * yv1 + l1 * vev.y;

      float ssq = yq0 * yq0 + yq1 * yq1;
      float ssk = yk0 * yk0 + yk1 * yk1;
#pragma unroll
      for (int off = 32; off > 0; off >>= 1) {
        ssq += __shfl_xor(ssq, off);
        ssk += __shfl_xor(ssk, off);
      }
      float rq = rsqrtf(ssq + 1e-6f) * QSCALE;
      float rk = rsqrtf(ssk + 1e-6f);

      f32x2 kk; kk.x = yk0 * rk; kk.y = yk1 * rk;
      f32x2 qq; qq.x = yq0 * rq; qq.y = yq1 * rq;
      f32x2 vv; vv.x = v0; vv.y = v1;
      *(f32x2*)&kL2[SL20(lr, c)] = kk;
      *(f32x2*)&qL2[lr * 132 + c] = qq;
      *(f32x2*)&vL2[lr * 128 + c] = vv;

      f32x2 gv = *(const f32x2*)(gbuf + (size_t)rr * 2048 + cg);
      float g0 = gv.x + dt2.x, g1 = gv.y + dt2.y;
      float sp0 = (g0 > 20.f) ? g0 : log1pf(__expf(fminf(g0, 20.f)));
      float sp1 = (g1 > 20.f) ? g1 : log1pf(__expf(fminf(g1, 20.f)));
      gl0[i] = -Aexp * sp0;
      gl1[i] = -Aexp * sp1;
    }
    // per-wave cumsum
    {
      float r0 = 0.f, r1 = 0.f;
#pragma unroll
      for (int i = 0; i < 8; ++i) { r0 += gl0[i]; gl0[i] = r0; r1 += gl1[i]; gl1[i] = r1; }
      csumW[w * 128 + c] = r0;
      csumW[w * 128 + c + 1] = r1;
    }
    if (tid < 32) betaL[tid] = betaT[(size_t)h * SEQL + cc * 32 + tid];
    __syncthreads();
    // cross-wave prefix, write GL
    {
      float p0 = 0.f, p1 = 0.f;
      for (int wp = 0; wp < w; ++wp) { p0 += csumW[wp * 128 + c]; p1 += csumW[wp * 128 + c + 1]; }
#pragma unroll
      for (int i = 0; i < 8; ++i) {
        f32x2 gg; gg.x = gl0[i] + p0; gg.y = gl1[i] + p1;
        *(f32x2*)&GL2[SL20(w * 8 + i, c)] = gg;
      }
    }
  }
  __syncthreads();

  // ======== phase 2: pairs A[t][i], B[t][i] (interleaved rows, conflict-free) ========
  {
    const int tg = lane >> 3, s8 = lane & 7;
    const int tt = w + 4 * tg;              // wave w owns rows {w, w+4, ..., w+28}
    const int ds = s8 * 20;                 // slice base (dwords) within row

    float Gt[16], kt[16], qt[16];
#pragma unroll
    for (int j = 0; j < 16; j += 4) {
      *(f32x4*)&Gt[j] = *(const f32x4*)&GL2[tt * 160 + ds + j];
      *(f32x4*)&kt[j] = *(const f32x4*)&kL2[tt * 160 + ds + j];
      *(f32x4*)&qt[j] = *(const f32x4*)&qL2[tt * 132 + s8 * 16 + j];
    }
    {
      float sA = 0.f, sB = 0.f;
#pragma unroll
      for (int j = 0; j < 16; ++j) { sA = fmaf(kt[j], kt[j], sA); sB = fmaf(qt[j], kt[j], sB); }
      sA += __shfl_xor(sA, 1); sA += __shfl_xor(sA, 2); sA += __shfl_xor(sA, 4);
      sB += __shfl_xor(sB, 1); sB += __shfl_xor(sB, 2); sB += __shfl_xor(sB, 4);
      if (s8 == 0) { ALB[tt][tt] = sA; Bdiag[tt] = sB; }
    }
    const int ibound = 28 + w;
    for (int i = 0; i < ibound; ++i) {
      if (i < tt) {
        float sA = 0.f, sB = 0.f;
#pragma unroll
        for (int jj = 0; jj < 4; ++jj) {
          f32x4 Gi = *(const f32x4*)&GL2[i * 160 + ds + jj * 4];
          f32x4 ki = *(const f32x4*)&kL2[i * 160 + ds + jj * 4];
#pragma unroll
          for (int u = 0; u < 4; ++u) {
            float e = __expf(Gt[jj * 4 + u] - Gi[u]);
            float kid = ki[u] * e;
            sA = fmaf(kt[jj * 4 + u], kid, sA);
            sB = fmaf(qt[jj * 4 + u], kid, sB);
          }
        }
        sA += __shfl_xor(sA, 1); sA += __shfl_xor(sA, 2); sA += __shfl_xor(sA, 4);
        sB += __shfl_xor(sB, 1); sB += __shfl_xor(sB, 2); sB += __shfl_xor(sB, 4);
        if (s8 == 0) { ALB[tt][i] = sA; ALB[i][tt] = sB; }
      }
    }
  }
  __syncthreads();

  // ======== phase 3: KbarT + substitution + Qt/oloc ========
  const int col = tid & 127, half = tid >> 7;
  const size_t rowbase = (size_t)(cc * 32) * 2048 + h * 128 + col;
  const int rbase = half * 16;
  {
    const float g31 = GL2[SL20(31, col)];
    size_t kb = hc * 4096 + (size_t)col * 32;
#pragma unroll
    for (int i = 0; i < 16; ++i) {
      int r = rbase + i;
      float kv = kL2[SL20(r, col)] * __expf(g31 - GL2[SL20(r, col)]);
      KTh[kb + r] = __float2bfloat16(kv);
    }
  }

  if (half == 0) {
    float expg[32];
#pragma unroll
    for (int r = 0; r < 32; ++r) expg[r] = __expf(GL2[SL20(r, col)]);

    float uvr[32], wr[32];
#pragma unroll
    for (int r = 0; r < 32; ++r) {
      float suv = 0.f, sw = 0.f;
#pragma unroll
      for (int j = 0; j < 32; ++j) {
        if (j < r) { float a = ALB[r][j]; suv = fmaf(a, uvr[j], suv); sw = fmaf(a, wr[j], sw); }
      }
      float br = betaL[r];
      float khr = kL2[SL20(r, col)] * expg[r];
      uvr[r] = br * (vL2[r * 128 + col] - suv);
      wr[r] = br * (khr - sw);
      uvS[rowbase + (size_t)r * 2048] = __float2bfloat16(uvr[r]);
      Xgh[hc * 8192 + (size_t)(32 + r) * 128 + col] = __float2bfloat16(wr[r]);
    }

#pragma unroll
    for (int r = 0; r < 32; ++r) {
      float qtv = qL2[r * 132 + col] * expg[r];
      float ol = 0.f;
#pragma unroll
      for (int j = 0; j < 32; ++j) {
        if (j < r) { float b = ALB[j][r]; qtv = fmaf(-b, wr[j], qtv); ol = fmaf(b, uvr[j], ol); }
      }
      { float b = Bdiag[r]; qtv = fmaf(-b, wr[r], qtv); ol = fmaf(b, uvr[r], ol); }
      Xgh[hc * 8192 + (size_t)r * 128 + col] = __float2bfloat16(qtv);
      olocS[rowbase + (size_t)r * 2048] = __float2bfloat16(ol);
    }
    Pg[hc * 128 + col] = expg[31];
  }
}

// ---------------- sequential chunk scan: S in MFMA accumulators, reg-prefetched ----------------
#define STP 136
#define UTP 40

struct ChunkOps {
  bf16x8 ah[4];
  bf16x8 kah[2];
  f32x4 pvv[2];
  float pB[4];
};

__global__ __launch_bounds__(256) void kda_seq(
    const __hip_bfloat16* __restrict__ Xgh, const __hip_bfloat16* __restrict__ KTh,
    const __hip_bfloat16* __restrict__ uvS, const __hip_bfloat16* __restrict__ olocS,
    const float* __restrict__ Pg, float* __restrict__ obuf)
{
  __shared__ __hip_bfloat16 STh[16 * STP], STl[16 * STP];
  __shared__ __hip_bfloat16 UTh[16 * UTP];
  const int tid = threadIdx.x;
  const int w = tid >> 6, lane = tid & 63, l15 = lane & 15, l4 = lane >> 4;
  const int h = blockIdx.x >> 3, vq = blockIdx.x & 7;
  const int v0 = vq * 16;
  const int r0 = (w & 1) * 16 + l4 * 4;
  const int isO = (w < 2);

  for (int i = tid; i < 16 * STP; i += 256) {
    STh[i] = __float2bfloat16(0.f);
    STl[i] = __float2bfloat16(0.f);
  }
  __syncthreads();

  f32x4 S[2] = {};

  auto loadops = [&](ChunkOps& o, int c) {
    const size_t hc = (size_t)h * 64 + c;
    const __hip_bfloat16* xh = Xgh + hc * 8192 + (size_t)(w * 16 + l15) * 128 + l4 * 8;
#pragma unroll
    for (int kk = 0; kk < 4; ++kk) o.ah[kk] = *(const bf16x8*)(xh + kk * 32);
    const __hip_bfloat16* pb = (isO ? olocS : uvS) + (size_t)(c * 32 + r0) * 2048 + h * 128 + v0 + l15;
#pragma unroll
    for (int r = 0; r < 4; ++r) o.pB[r] = __bfloat162float(pb[(size_t)r * 2048]);
#pragma unroll
    for (int mi = 0; mi < 2; ++mi) {
      const int kd = (w * 2 + mi) * 16;
      o.kah[mi] = *(const bf16x8*)(KTh + hc * 4096 + (size_t)(kd + l15) * 32 + l4 * 8);
      o.pvv[mi] = *(const f32x4*)(Pg + hc * 128 + kd + l4 * 4);
    }
  };

  auto body = [&](ChunkOps& o, int c) {
    f32x4 Y = {};
#pragma unroll
    for (int kk = 0; kk < 4; ++kk) {
      const int so = l15 * STP + kk * 32 + l4 * 8;
      bf16x8 bh = *(const bf16x8*)(STh + so);
      bf16x8 bl = *(const bf16x8*)(STl + so);
      Y = __builtin_amdgcn_mfma_f32_16x16x32_bf16(o.ah[kk], bh, Y, 0, 0, 0);
      Y = __builtin_amdgcn_mfma_f32_16x16x32_bf16(o.ah[kk], bl, Y, 0, 0, 0);
    }

    if (isO) {
      size_t ob = (size_t)(c * 32 + r0) * 2048 + h * 128 + v0 + l15;
#pragma unroll
      for (int r = 0; r < 4; ++r)
        obuf[ob + (size_t)r * 2048] = Y[r] + o.pB[r];
    } else {
      union { __hip_bfloat16 b[4]; unsigned long long u; } uh;
#pragma unroll
      for (int r = 0; r < 4; ++r)
        uh.b[r] = __float2bfloat16(o.pB[r] - Y[r]);
      *(unsigned long long*)(UTh + l15 * UTP + r0) = uh.u;
    }
    __syncthreads();

#pragma unroll
    for (int mi = 0; mi < 2; ++mi) S[mi] *= o.pvv[mi];
    {
      bf16x8 ubh = *(const bf16x8*)(UTh + l15 * UTP + l4 * 8);
#pragma unroll
      for (int mi = 0; mi < 2; ++mi)
        S[mi] = __builtin_amdgcn_mfma_f32_16x16x32_bf16(o.kah[mi], ubh, S[mi], 0, 0, 0);
    }

#pragma unroll
    for (int mi = 0; mi < 2; ++mi) {
      const int kd0 = (w * 2 + mi) * 16 + l4 * 4;
      union { __hip_bfloat16 b[4]; unsigned long long u; } sh, sl;
#pragma unroll
      for (int r = 0; r < 4; ++r) {
        __hip_bfloat16 hh = __float2bfloat16(S[mi][r]);
        sh.b[r] = hh;
        sl.b[r] = __float2bfloat16(S[mi][r] - __bfloat162float(hh));
      }
      *(unsigned long long*)(STh + l15 * STP + kd0) = sh.u;
      *(unsigned long long*)(STl + l15 * STP + kd0) = sl.u;
    }
    __syncthreads();
  };

  ChunkOps A_, B_;
  loadops(A_, 0);
  for (int c = 0; c < 64; c += 2) {
    loadops(B_, c + 1);
    body(A_, c);
    if (c + 2 < 64) loadops(A_, c + 2);
    body(B_, c + 1);
  }
}

// ---------------- sigmoid-gated RMSNorm -> bf16 ----------------
__global__ __launch_bounds__(256) void rmsgate_kernel(
    const float* __restrict__ o, const float* __restrict__ gate,
    const float* __restrict__ bg2, const float* __restrict__ norm_w,
    __hip_bfloat16* __restrict__ og)
{
  int row = blockIdx.x * 4 + (threadIdx.x >> 6);   // s*16 + h
  int lane = threadIdx.x & 63;
  int s = row >> 4, h = row & 15;
  int j = lane * 2;
  const float* p = o + (size_t)row * 128 + j;
  f32x2 v = *(const f32x2*)p;
  float ss = v.x * v.x + v.y * v.y;
#pragma unroll
  for (int off = 32; off > 0; off >>= 1) ss += __shfl_xor(ss, off);
  float rs = rsqrtf(ss * (1.f / 128.f) + 1e-6f);
  int c = h * 128 + j;
  float g0 = gate[(size_t)s * 2048 + c] + bg2[c];
  float g1 = gate[(size_t)s * 2048 + c + 1] + bg2[c + 1];
  float o0 = v.x * rs * norm_w[j] * (1.f / (1.f + expf(-g0)));
  float o1 = v.y * rs * norm_w[j + 1] * (1.f / (1.f + expf(-g1)));
  union { __hip_bfloat16 b[2]; unsigned int u; } pk2;
  pk2.b[0] = __float2bfloat16(o0);
  pk2.b[1] = __float2bfloat16(o1);
  *(unsigned int*)((char*)og + ((size_t)s * 2048 + c) * 2) = pk2.u;
}

// =====================================================================
extern "C" void kernel_launch(void* const* d_in, const int* in_sizes, int n_in,
                              void* d_out, int out_size, void* d_ws, size_t ws_size,
                              hipStream_t stream)
{
  const float* x      = (const float*)d_in[0];
  const float* ve     = (const float*)d_in[1];
  const float* lam    = (const float*)d_in[2];
  const float* Wq     = (const float*)d_in[3];
  const float* Wk     = (const float*)d_in[4];
  const float* Wv     = (const float*)d_in[5];
  const float* cwq    = (const float*)d_in[6];
  const float* cwk    = (const float*)d_in[7];
  const float* cwv    = (const float*)d_in[8];
  const float* Wf1    = (const float*)d_in[9];
  const float* Wf2    = (const float*)d_in[10];
  const float* Wb     = (const float*)d_in[11];
  const float* A_log  = (const float*)d_in[12];
  const float* dtb    = (const float*)d_in[13];
  const float* Wg1    = (const float*)d_in[14];
  const float* Wg2    = (const float*)d_in[15];
  const float* bg2    = (const float*)d_in[16];
  const float* norm_w = (const float*)d_in[17];
  const float* Wo     = (const float*)d_in[18];
  float* out = (float*)d_out;

  const size_t S2 = (size_t)2048 * 2048;

  char* p = (char*)d_ws;
  auto alloc = [&](size_t bytes) { char* r = p; p += (bytes + 255) & ~(size_t)255; return r; };

  __hip_bfloat16* xb     = (__hip_bfloat16*)alloc(S2 * 2);
  __hip_bfloat16* WoT    = (__hip_bfloat16*)alloc(S2 * 2);
  __hip_bfloat16* Wf2hT  = (__hip_bfloat16*)alloc(2048 * 128 * 2);
  __hip_bfloat16* Wf2lT  = (__hip_bfloat16*)alloc(2048 * 128 * 2);
  __hip_bfloat16* Wg2T   = (__hip_bfloat16*)alloc(2048 * 128 * 2);
  __hip_bfloat16* Wfg1hT = (__hip_bfloat16*)alloc((size_t)256 * 2048 * 2);
  __hip_bfloat16* Wfg1lT = (__hip_bfloat16*)alloc((size_t)256 * 2048 * 2);
  __hip_bfloat16* f1g1h  = (__hip_bfloat16*)alloc((size_t)2048 * 256 * 2);
  __hip_bfloat16* f1g1l  = (__hip_bfloat16*)alloc((size_t)2048 * 256 * 2);
  float* betaT = (float*)alloc((size_t)2048 * 16 * 4);
  float* qkv   = (float*)alloc(3 * S2 * 4);          // [2048][6144] f32
  float* gbuf  = (float*)alloc(S2 * 4);
  float* gatebuf = (float*)alloc(S2 * 4);
  __hip_bfloat16* uvS   = (__hip_bfloat16*)alloc(S2 * 4);   // bf16 in first half; alloc kept f32-size for overlays
  __hip_bfloat16* olocS = (__hip_bfloat16*)alloc(S2 * 4);
  __hip_bfloat16* Xgh = (__hip_bfloat16*)alloc(S2 * 4);   // 16MB: 1024 hc x 64 rows x 128 cols bf16
  __hip_bfloat16* KTh = (__hip_bfloat16*)alloc(S2 * 2);   // 8MB: 1024 hc x 128 x 32 bf16
  float* Pg    = (float*)alloc((size_t)1024 * 128 * 4);

  // overlays (timeline-checked):
  // WqkvT (24MB, steps 2-3) -> uvS alloc (16MB) + olocS alloc [0:8MB]; first rewritten at kda_pref (step 7)
  __hip_bfloat16* WqkvT = (__hip_bfloat16*)uvS;
  // xlo (8MB, steps 1-4) -> olocS alloc [8MB:16MB] (disjoint from WqkvT and from olocS bf16 payload [0:8MB])
  __hip_bfloat16* xlo = (__hip_bfloat16*)((char*)olocS + S2 * 2);
  // fpart (16MB, step 4 only) -> inside Xgh (16MB); Xgh written later at step 7
  float* fpart = (float*)Xgh;
  float* obuf  = gbuf;                          // gbuf dead after kda_pref
  __hip_bfloat16* og = (__hip_bfloat16*)qkv;    // qkv dead after kda_pref; og = first 8MB
  float* wpart = (float*)((char*)qkv + 16 * 1024 * 1024);  // 32MB partials for Wo split-K (disjoint from og)

  // 1. split-cast x
  cast_split_kernel<<<4096, 256, 0, stream>>>(x, xb, xlo, (int)(S2 / 4));

  // 2. weight transposes (Wq/Wk/Wv merged; Wf1|Wg1 merged into [256][2048])
  transpose_cast_kernel<<<dim3(64, 64), 256, 0, stream>>>(Wq, WqkvT, nullptr, 2048, 2048);
  transpose_cast_kernel<<<dim3(64, 64), 256, 0, stream>>>(Wk, WqkvT + 2048 * 2048, nullptr, 2048, 2048);
  transpose_cast_kernel<<<dim3(64, 64), 256, 0, stream>>>(Wv, WqkvT + 2 * 2048 * 2048, nullptr, 2048, 2048);
  transpose_cast_kernel<<<dim3(64, 64), 256, 0, stream>>>(Wo, WoT, nullptr, 2048, 2048);
  transpose_cast_kernel<<<dim3(4, 64), 256, 0, stream>>>(Wf1, Wfg1hT, Wfg1lT, 2048, 128);
  transpose_cast_kernel<<<dim3(4, 64), 256, 0, stream>>>(Wg1, Wfg1hT + 128 * 2048, nullptr, 2048, 128);
  hipMemsetAsync(Wfg1lT + 128 * 2048, 0, (size_t)128 * 2048 * 2, stream);
  transpose_cast_kernel<<<dim3(64, 4), 256, 0, stream>>>(Wf2, Wf2hT, Wf2lT, 128, 2048);
  transpose_cast_kernel<<<dim3(64, 4), 256, 0, stream>>>(Wg2, Wg2T, nullptr, 128, 2048);

  // 3. merged QKV projection via 8-phase 256^2 GEMM: qkv[2048][6144]
  gemm_bt256<<<dim3(24, 8, 1), 512, 0, stream>>>(xb, WqkvT, qkv, 2048, 6144, 2048, 2048, 32);

  // 4. merged f1|g1 stage (split-K z=8, 3-pass split precision)
  gemm_btsplit<<<dim3(2, 16, 8), 256, 0, stream>>>(xb, xlo, Wfg1hT, Wfg1lT, fpart,
                                                   2048, 256, 2048, 2048, 256);
  reduce8_kernel<<<512, 256, 0, stream>>>(fpart, f1g1h, f1g1l, 131072, (size_t)2048 * 256);

  // 5. second stages: g = f1 @ Wf2 (split); gate = g1 @ Wg2
  gemm_btsplit<<<dim3(16, 16), 256, 0, stream>>>(f1g1h, f1g1l, Wf2hT, Wf2lT, gbuf,
                                                 2048, 2048, 256, 128, 128);
  gemm_bt<<<dim3(16, 16), 256, 0, stream>>>(f1g1h + 128, Wg2T, gatebuf,
                                            2048, 2048, 256, 128, 128, 0);

  // 6. beta
  beta_kernel<<<128, 256, 0, stream>>>(x, Wb, betaT);

  // 7. fused prep + chunk-local precompute
  kda_pref<<<1024, 256, 0, stream>>>(qkv, ve, lam, cwq, cwk, cwv, gbuf, dtb, A_log, betaT,
                                     Xgh, KTh, uvS, olocS, Pg);

  // 8. sequential chunk scan (128 blocks: h x v-eighth)
  kda_seq<<<128, 256, 0, stream>>>(Xgh, KTh, uvS, olocS, Pg, obuf);

  // 9. gated rmsnorm -> bf16 (og aliases qkv[0:8MB])
  rmsgate_kernel<<<8192, 256, 0, stream>>>(obuf, gatebuf, bg2, norm_w, og);

  // 10. output projection: 256^2 8-phase, split-K z=2 + reduce
  gemm_bt256<<<dim3(8, 8, 2), 512, 0, stream>>>(og, WoT, wpart, 2048, 2048, 2048, 2048, 16);
  reduce2_kernel<<<4096, 256, 0, stream>>>(wpart, out, (int)(S2 / 4));
}